// Round 10
// baseline (341.913 us; speedup 1.0000x reference)
//
#include <hip/hip_runtime.h>

// Self-attention forward. Inputs f32: x[4,2048,1024], Wqkv[1024,3072],
// bqkv[3072], Wout[1024,1024], bout[1024]; mask[4,2048,2048] int32.
// Output f32 [4,2048,1024].
//
// Round-16: 2 blocks/CU. Rounds 2-9: four different in-block schedules all
// plateau at K1 ~63-70us / MfmaUtil ~30% -> shared binder is the single
// 512-thread block per CU in barrier lockstep (no independent waves across
// sync points; m97's 874 TF came from ~3 desynced blocks/CU, m114).
// New gemm128ra: 128x128 tile, 256 thr (4 waves, wave 64x64), BK=32,
// ring-4 LDS = 64 KB -> 2 resident blocks/CU.
//   - Per phase (1 K-tile): 8 ds_read_b128 (next tile's frags, read-ahead)
//     | stage tile t+3 (4 gld16, into slot freed 2 barriers ago) | 16 MFMA
//     | vmcnt(4) (FIFO: retires tile t+2, read next phase) | barrier.
//   - 4-phase unrolled loop: all slot / frag-set indices compile-time.
//   - Row-pair LDS layout for BK=32: LDS[64 row'][8 chunk16B]; chunk c at
//     phys = c ^ (row'&7); logical (mrow,k) = (row'*2 + (c>>2), (c&3)*8).
//     Frag read: 64 lanes hit 64 distinct 16B slots of a 1KB block
//     (conflict-free); staging source inverse-permuted (rule 21).
//   - Exact rounds at 2 blocks/CU: K1 1536=3.0, K2 1024=2.0, K4/K5 512=1.0.

typedef __attribute__((ext_vector_type(8))) short short8;
typedef __attribute__((ext_vector_type(4))) float f32x4;
typedef unsigned short u16;

#define SEQ 2048
#define NB 4

static __device__ __forceinline__ u16 f2bf(float f) {
    unsigned int u = __builtin_bit_cast(unsigned int, f);
    u += 0x7fffu + ((u >> 16) & 1u);   // RNE
    return (u16)(u >> 16);
}
static __device__ __forceinline__ float bf2f(u16 h) {
    unsigned int u = ((unsigned int)h) << 16;
    return __builtin_bit_cast(float, u);
}

// async global->LDS, 16 bytes/lane. LDS dest = wave-uniform base + lane*16.
static __device__ __forceinline__ void gld16(u16* l, const u16* g) {
    __builtin_amdgcn_global_load_lds(
        (__attribute__((address_space(1))) void*)(g),
        (__attribute__((address_space(3))) void*)(l),
        16, 0, 0);
}

// f32 -> bf16, 8 elems/thread.
__global__ __launch_bounds__(256) void cvt_bf16(const float* __restrict__ s,
                                                u16* __restrict__ d, long n) {
    long i = ((long)blockIdx.x * 256 + threadIdx.x) * 8;
    if (i >= n) return;
    f32x4 a = *(const f32x4*)(s + i);
    f32x4 b = *(const f32x4*)(s + i + 4);
    short8 o;
    o[0] = (short)f2bf(a.x); o[1] = (short)f2bf(a.y);
    o[2] = (short)f2bf(a.z); o[3] = (short)f2bf(a.w);
    o[4] = (short)f2bf(b.x); o[5] = (short)f2bf(b.y);
    o[6] = (short)f2bf(b.z); o[7] = (short)f2bf(b.w);
    *(short8*)(d + i) = o;
}

// f32 [R][C] -> bf16 [C][R] (transpose + convert), 32x32 LDS tiles.
__global__ __launch_bounds__(256) void transpose_cvt(const float* __restrict__ in,
                                                     u16* __restrict__ out,
                                                     int R, int C) {
    __shared__ float t[32][33];
    const int c0 = blockIdx.x * 32;
    const int r0 = blockIdx.y * 32;
    const int x = threadIdx.x & 31;
    const int y = (threadIdx.x >> 5) * 4;
    #pragma unroll
    for (int i = 0; i < 4; i++)
        t[y + i][x] = in[(long)(r0 + y + i) * C + c0 + x];
    __syncthreads();
    #pragma unroll
    for (int i = 0; i < 4; i++)
        out[(long)(c0 + y + i) * R + r0 + x] = f2bf(t[x][y + i]);
}

// V slice of qkv -> vt [b][1024 d][2048 s]. bf16 32x32 tile transpose.
__global__ __launch_bounds__(256) void transpose_v(const u16* __restrict__ qkv,
                                                   u16* __restrict__ vt) {
    __shared__ u16 t[32][33];
    const int b = blockIdx.z;
    const int s0 = blockIdx.y * 32;
    const int d0 = blockIdx.x * 32;
    const int x = threadIdx.x & 31;
    const int y = (threadIdx.x >> 5) * 4;
    const u16* src = qkv + (long)b * SEQ * 3072 + 2048;
    u16* dst = vt + (long)b * 1024 * SEQ;
    #pragma unroll
    for (int i = 0; i < 4; i++)
        t[y + i][x] = src[(long)(s0 + y + i) * 3072 + d0 + x];
    __syncthreads();
    #pragma unroll
    for (int i = 0; i < 4; i++)
        dst[(long)(d0 + y + i) * SEQ + s0 + x] = t[x][y + i];
}

// bijective XCD swizzle of the flat (y*gx+x) tile id; requires nwg%8==0.
static __device__ __forceinline__ int xcd_swz(int flat, int nwg) {
    return (flat & 7) * (nwg >> 3) + (flat >> 3);
}

// bf16 MFMA GEMM, 128x128 tile, BK=32, ring-4, read-ahead, 2 blocks/CU.
// C[m][n] = sum_k A[m][k] * Bt[n][k]   (Bt = B^T, [N][K] row-major).
// EPI 0: bf16 out + optional f32 bias.  EPI 1: bf16 out, *scale.
// EPI 2: f32 out + f32 bias.
// Requires: M%128==0, N%128==0, K%128==0 (nt=K/32 multiple of 4, >=8),
// (gx*gy)%8==0.
template<int EPI>
__global__ __launch_bounds__(256, 2) void gemm128ra(
    const u16* __restrict__ Ap, long lda, long aBatch,
    const u16* __restrict__ Bp, long ldb, long bBatch,
    void* __restrict__ Cp, long ldc, long cBatch,
    const float* __restrict__ bias,
    float scale, int K)
{
    // 4 slots x (A[128][32] 8KB + B[128][32] 8KB) = 64 KB.
    // u16 layout per slot (8192): A at 0, B at 4096; each is
    // [64 row'][8 phys-chunks of 8 u16]; chunk c stored at phys=c^(row'&7);
    // logical: mrow = row'*2 + (c>>2), k = (c&3)*8.
    __shared__ __attribute__((aligned(16))) u16 lds[32768];

    const int tid  = threadIdx.x;
    const int lane = tid & 63;
    const int wave = tid >> 6;          // 0..3
    const int wr   = wave >> 1;         // 0..1: 64-row band
    const int wc   = wave & 1;          // 0..1: 64-col band
    const int m16  = lane & 15;
    const int quad = lane >> 4;
    const int b    = blockIdx.z;

    const int gx = gridDim.x;
    const int flat = xcd_swz(blockIdx.y * gx + blockIdx.x, gx * gridDim.y);
    const long m0  = (long)(flat / gx) * 128;
    const long n0  = (long)(flat % gx) * 128;

    const u16* A = Ap + (long)b * aBatch;
    const u16* B = Bp + (long)b * bBatch;

    // staging lane constants. gld#i dest (u16): slot*8192 [+4096 B] +
    // i*2048 + wave*512 + lane*8  ->  row' = i*32 + wave*8 + (lane>>3),
    // phys = lane&7, c = phys ^ (row'&7) = (lane&7)^(lane>>3).
    const int c8    = (lane & 7) ^ (lane >> 3);
    const int srow2 = wave * 16 + (lane >> 3) * 2 + (c8 >> 2);
    const int skk   = (c8 & 3) * 8;
    const u16* aS = A + (m0 + srow2) * lda + skk;
    const u16* bS = B + (n0 + srow2) * ldb + skk;

    // frag read constants: lane (quad,m16) of frag mi reads
    // mrow = wr*64+mi*16+m16, k = quad*8:
    // row' = wr*32+mi*8+(m16>>1), phys = ((m16&1)*4+quad)^(m16>>1).
    const int phys = (((m16 & 1) << 2) + quad) ^ (m16 >> 1);
    const int fro  = (m16 >> 1) * 64 + phys * 8;
    const int aro  = wr * 2048 + fro;   // + mi*512
    const int bro  = wc * 2048 + fro;   // + 4096 + ni*512

    short8 af[2][4], bf[2][4];          // [set][mi/ni]
    f32x4 acc[4][4];                    // [mi][ni]
    #pragma unroll
    for (int mi = 0; mi < 4; mi++)
        #pragma unroll
        for (int ni = 0; ni < 4; ni++)
            acc[mi][ni] = (f32x4){0.f, 0.f, 0.f, 0.f};

    auto STAGE = [&](int slot, long koff) {
        u16* la = (u16*)lds + slot * 8192 + wave * 512;
        const u16* ga = aS + koff;
        gld16(la,        ga);
        gld16(la + 2048, ga + (long)64 * lda);
        u16* lb = (u16*)lds + slot * 8192 + 4096 + wave * 512;
        const u16* gb = bS + koff;
        gld16(lb,        gb);
        gld16(lb + 2048, gb + (long)64 * ldb);
    };
    auto RD = [&](int set, int slot) {
        const u16* p = (const u16*)lds + slot * 8192;
        #pragma unroll
        for (int mi = 0; mi < 4; mi++)
            af[set][mi] = *(const short8*)(p + aro + mi * 512);
        #pragma unroll
        for (int ni = 0; ni < 4; ni++)
            bf[set][ni] = *(const short8*)(p + 4096 + bro + ni * 512);
    };
    auto MMA = [&](int set) {
        __builtin_amdgcn_s_setprio(1);
        #pragma unroll
        for (int mi = 0; mi < 4; mi++)
            #pragma unroll
            for (int ni = 0; ni < 4; ni++)
                acc[mi][ni] = __builtin_amdgcn_mfma_f32_16x16x32_bf16(
                    af[set][mi], bf[set][ni], acc[mi][ni], 0, 0, 0);
        __builtin_amdgcn_s_setprio(0);
    };

    const int nt = K >> 5;              // 32-wide K-tiles (nt%4==0, >=8)
    const int last = (nt - 1) * 32;

    // prologue: stage tiles 0,1,2 (12 gld16, FIFO); vmcnt(4) retires
    // tiles 0,1 (leaves tile 2 in flight); read tile 0 frags into set 0.
    STAGE(0, 0); STAGE(1, 32); STAGE(2, 64);
    asm volatile("s_waitcnt vmcnt(4)");
    __builtin_amdgcn_s_barrier();
    RD(0, 0);

    // phase t: RD tile t+1 (slot (t+1)&3) into set (t+1)&1; STAGE tile t+3
    // (slot (t+3)&3 - freed 2 barriers ago); MMA tile t (set t&1);
    // vmcnt(4): outstanding {t+2,t+3}=8 -> retires t+2 (read next phase).
    // Tail: stage koff clamps to last tile (dead restages); final phase's
    // RD (tile nt) loads dead data into a set never consumed.
    #pragma unroll 1
    for (int t = 0; t < nt; t += 4) {
        RD(1, 1); STAGE(3, (long)(t + 3 < nt ? (t + 3) * 32 : last));
        MMA(0);
        asm volatile("s_waitcnt vmcnt(4)");
        __builtin_amdgcn_s_barrier();

        RD(0, 2); STAGE(0, (long)(t + 4 < nt ? (t + 4) * 32 : last));
        MMA(1);
        asm volatile("s_waitcnt vmcnt(4)");
        __builtin_amdgcn_s_barrier();

        RD(1, 3); STAGE(1, (long)(t + 5 < nt ? (t + 5) * 32 : last));
        MMA(0);
        asm volatile("s_waitcnt vmcnt(4)");
        __builtin_amdgcn_s_barrier();

        RD(0, 0); STAGE(2, (long)(t + 6 < nt ? (t + 6) * 32 : last));
        MMA(1);
        asm volatile("s_waitcnt vmcnt(4)");
        __builtin_amdgcn_s_barrier();
    }

    // drain async LDS writes before epilogue/endpgm (LDS realloc hazard)
    asm volatile("s_waitcnt vmcnt(0)");

    // D mapping per 16x16 frag: col = lane&15, row = quad*4 + r.
    const long row0 = m0 + wr * 64 + quad * 4;
    #pragma unroll
    for (int ni = 0; ni < 4; ni++) {
        const long col = n0 + wc * 64 + ni * 16 + m16;
        if (EPI == 0) {
            u16* C = (u16*)Cp + (long)b * cBatch;
            const float bv = bias ? bias[col] : 0.f;
            #pragma unroll
            for (int mi = 0; mi < 4; mi++)
                #pragma unroll
                for (int r = 0; r < 4; r++)
                    C[(row0 + mi * 16 + r) * ldc + col] =
                        f2bf(acc[mi][ni][r] + bv);
        } else if (EPI == 1) {
            u16* C = (u16*)Cp + (long)b * cBatch;
            #pragma unroll
            for (int mi = 0; mi < 4; mi++)
                #pragma unroll
                for (int r = 0; r < 4; r++)
                    C[(row0 + mi * 16 + r) * ldc + col] =
                        f2bf(acc[mi][ni][r] * scale);
        } else {
            float* C = (float*)Cp + (long)b * cBatch;
            const float bv = bias ? bias[col] : 0.f;
            #pragma unroll
            for (int mi = 0; mi < 4; mi++)
                #pragma unroll
                for (int r = 0; r < 4; r++)
                    C[(row0 + mi * 16 + r) * ldc + col] =
                        acc[mi][ni][r] + bv;
        }
    }
}

// in-place masked row softmax over 2048 bf16 (f32 math). 1 block per row.
__global__ __launch_bounds__(256) void softmax2048(u16* __restrict__ S,
                                                   const int* __restrict__ mask) {
    const long row = blockIdx.x;
    u16* p = S + row * SEQ;
    const int* mrow = mask + row * SEQ;
    const int tid = threadIdx.x;

    short8 v = *(const short8*)(p + tid * 8);
    uint4 mw0 = *(const uint4*)(mrow + tid * 8);
    uint4 mw1 = *(const uint4*)(mrow + tid * 8 + 4);
    const unsigned int* mwv = (const unsigned int*)&mw0;

    float f[8];
    #pragma unroll
    for (int j = 0; j < 8; j++) {
        const unsigned int mv = (j < 4) ? mwv[j] : ((const unsigned int*)&mw1)[j - 4];
        f[j] = (mv == 0u) ? 1e-10f : bf2f((u16)v[j]);
    }

    float m = f[0];
    #pragma unroll
    for (int j = 1; j < 8; j++) m = fmaxf(m, f[j]);
    #pragma unroll
    for (int i = 1; i < 64; i <<= 1) m = fmaxf(m, __shfl_xor(m, i));

    __shared__ float redm[4], reds[4];
    if ((tid & 63) == 0) redm[tid >> 6] = m;
    __syncthreads();
    m = fmaxf(fmaxf(redm[0], redm[1]), fmaxf(redm[2], redm[3]));

    float e[8], s = 0.f;
    #pragma unroll
    for (int j = 0; j < 8; j++) { e[j] = __expf(f[j] - m); s += e[j]; }
    #pragma unroll
    for (int i = 1; i < 64; i <<= 1) s += __shfl_xor(s, i);
    if ((tid & 63) == 0) reds[tid >> 6] = s;
    __syncthreads();
    s = reds[0] + reds[1] + reds[2] + reds[3];

    const float inv = 1.f / s;
    short8 o;
    #pragma unroll
    for (int j = 0; j < 8; j++) o[j] = (short)f2bf(e[j] * inv);
    *(short8*)(p + tid * 8) = o;
}

extern "C" void kernel_launch(void* const* d_in, const int* in_sizes, int n_in,
                              void* d_out, int out_size, void* d_ws, size_t ws_size,
                              hipStream_t stream) {
    const float* x    = (const float*)d_in[0];
    const int*   mask = (const int*)d_in[1];
    const float* Wqkv = (const float*)d_in[2];
    const float* bqkv = (const float*)d_in[3];
    const float* Wout = (const float*)d_in[4];
    const float* bout = (const float*)d_in[5];
    float* out = (float*)d_out;

    char* ws = (char*)d_ws;
    // ws layout, total 102,760,448 bytes:
    //   [0,        16777216) xh  bf16 [8192][1024]          (cvt -> K1)
    //   [16777216, 23068672) wqt bf16 [3072][1024]          (cvt -> K1)
    //   [0,        33554432) sc  bf16 [4][2048][2048]       (K2 -> K4; xh,wqt dead)
    //   [33554432, 35651584) wot bf16 [1024][1024]          (cvt -> K5)
    //   [35651584, 85983232) qkv bf16 [8192][3072]          (K1 -> K2)
    //   [35651584, 52428800) attn bf16 [8192][1024]         (K4 -> K5; qkv dead)
    //   [85983232,102760448) vt  bf16 [4][1024][2048]       (transpose_v -> K4)
    u16* xh   = (u16*)(ws + 0);
    u16* wqt  = (u16*)(ws + 16777216);
    u16* sc   = (u16*)(ws + 0);
    u16* wot  = (u16*)(ws + 33554432);
    u16* qkv  = (u16*)(ws + 35651584);
    u16* attn = (u16*)(ws + 35651584);
    u16* vt   = (u16*)(ws + 85983232);

    cvt_bf16<<<4096, 256, 0, stream>>>(x, xh, 8388608);
    transpose_cvt<<<dim3(96, 32), 256, 0, stream>>>(Wqkv, wqt, 1024, 3072);
    transpose_cvt<<<dim3(32, 32), 256, 0, stream>>>(Wout, wot, 1024, 1024);

    // K1: qkv = x @ Wqkv + bqkv   (M=8192, N=3072, K=1024), bf16 out
    //     24x64 = 1536 blocks = 3.0 rounds at 2 blocks/CU
    gemm128ra<0><<<dim3(24, 64, 1), 256, 0, stream>>>(
        xh, 1024, 0, wqt, 1024, 0, qkv, 3072, 0, bqkv, 1.f, 1024);

    // V slice -> vt [b][d][s]
    transpose_v<<<dim3(32, 64, NB), 256, 0, stream>>>(qkv, vt);

    // K2: sc[b] = (Q[b] @ K[b]^T)/32   (M=N=2048, K=1024), bf16 out
    //     16x16x4 = 1024 blocks = 2.0 rounds
    gemm128ra<1><<<dim3(16, 16, NB), 256, 0, stream>>>(
        qkv, 3072, (long)SEQ * 3072, qkv + 1024, 3072, (long)SEQ * 3072,
        sc, SEQ, (long)SEQ * SEQ, nullptr, 0.03125f, 1024);

    // K3: masked softmax rows (mask==0 -> 1e-10, f32 math, bf16 storage)
    softmax2048<<<dim3(NB * SEQ), 256, 0, stream>>>(sc, mask);

    // K4: attn[b] = P[b] @ V[b]   (M=2048, N=1024, K=2048), bf16 out
    //     8x16x4 = 512 blocks = 1.0 round
    gemm128ra<0><<<dim3(8, 16, NB), 256, 0, stream>>>(
        sc, SEQ, (long)SEQ * SEQ, vt, SEQ, (long)1024 * SEQ,
        attn, 1024, (long)SEQ * 1024, nullptr, 1.f, 2048);

    // K5: out = attn @ Wout + bout   (M=8192, N=1024, K=1024), f32 out
    //     8x64 = 512 blocks = 1.0 round
    gemm128ra<2><<<dim3(8, 64, 1), 256, 0, stream>>>(
        attn, 1024, 0, wot, 1024, 0, out, 1024, 0, bout, 1.f, 1024);
}

// Round 11
// 321.625 us; speedup vs baseline: 1.0631x; 1.0631x over previous
//
#include <hip/hip_runtime.h>

// Self-attention forward. Inputs f32: x[4,2048,1024], Wqkv[1024,3072],
// bqkv[3072], Wout[1024,1024], bout[1024]; mask[4,2048,2048] int32.
// Output f32 [4,2048,1024].
//
// Round-17: revert to the round-8 best (312us: n128 read-ahead GEMM
// everywhere) and delete work instead of re-rolling the schedule (five
// schedule variants all plateau at MfmaUtil ~30%):
//   - transpose_v ELIMINATED. K1 split: K1a computes Q,K into tight
//     qk[8192][2048] (512 blocks = 2.0 rounds); K1b computes V with a
//     TRANSPOSED epilogue (EPI=3) writing vt[b][1024 d][2048 s] directly
//     (256 blocks = 1.0 round). Same 3 total rounds as old K1, minus
//     transpose_v's 33.5 MB round trip + launch.
//   - EPI=3 store: acc rows r=0..3 are consecutive in vt -> one ushort4
//     per fragment (16x32B segments/wave-store; V writes only 16.8 MB).
//   - K2 operand stride tightens 3072 -> 2048 (qk layout).

typedef __attribute__((ext_vector_type(8))) short short8;
typedef __attribute__((ext_vector_type(4))) float f32x4;
typedef __attribute__((ext_vector_type(4))) unsigned short us4;
typedef unsigned short u16;

#define SEQ 2048
#define NB 4

static __device__ __forceinline__ u16 f2bf(float f) {
    unsigned int u = __builtin_bit_cast(unsigned int, f);
    u += 0x7fffu + ((u >> 16) & 1u);   // RNE
    return (u16)(u >> 16);
}
static __device__ __forceinline__ float bf2f(u16 h) {
    unsigned int u = ((unsigned int)h) << 16;
    return __builtin_bit_cast(float, u);
}

// async global->LDS, 16 bytes/lane. LDS dest = wave-uniform base + lane*16.
static __device__ __forceinline__ void gld16(u16* l, const u16* g) {
    __builtin_amdgcn_global_load_lds(
        (__attribute__((address_space(1))) void*)(g),
        (__attribute__((address_space(3))) void*)(l),
        16, 0, 0);
}

// f32 -> bf16, 8 elems/thread.
__global__ __launch_bounds__(256) void cvt_bf16(const float* __restrict__ s,
                                                u16* __restrict__ d, long n) {
    long i = ((long)blockIdx.x * 256 + threadIdx.x) * 8;
    if (i >= n) return;
    f32x4 a = *(const f32x4*)(s + i);
    f32x4 b = *(const f32x4*)(s + i + 4);
    short8 o;
    o[0] = (short)f2bf(a.x); o[1] = (short)f2bf(a.y);
    o[2] = (short)f2bf(a.z); o[3] = (short)f2bf(a.w);
    o[4] = (short)f2bf(b.x); o[5] = (short)f2bf(b.y);
    o[6] = (short)f2bf(b.z); o[7] = (short)f2bf(b.w);
    *(short8*)(d + i) = o;
}

// f32 [R][C] -> bf16 [C][R] (transpose + convert), 32x32 LDS tiles.
__global__ __launch_bounds__(256) void transpose_cvt(const float* __restrict__ in,
                                                     u16* __restrict__ out,
                                                     int R, int C) {
    __shared__ float t[32][33];
    const int c0 = blockIdx.x * 32;
    const int r0 = blockIdx.y * 32;
    const int x = threadIdx.x & 31;
    const int y = (threadIdx.x >> 5) * 4;
    #pragma unroll
    for (int i = 0; i < 4; i++)
        t[y + i][x] = in[(long)(r0 + y + i) * C + c0 + x];
    __syncthreads();
    #pragma unroll
    for (int i = 0; i < 4; i++)
        out[(long)(c0 + y + i) * R + r0 + x] = f2bf(t[x][y + i]);
}

// bijective XCD swizzle of the flat (y*gx+x) tile id; requires nwg%8==0.
static __device__ __forceinline__ int xcd_swz(int flat, int nwg) {
    return (flat & 7) * (nwg >> 3) + (flat >> 3);
}

// bf16 MFMA GEMM, 256x128 tile, 4-phase 2-buffer read-ahead pipeline
// (round-8 schedule, harness-verified at 312us total).
// C[m][n] = sum_k A[m][k] * Bt[n][k]   (Bt = B^T, [N][K] row-major).
// EPI 0: bf16 out + optional f32 bias.  EPI 1: bf16 out, *scale.
// EPI 2: f32 out + f32 bias.
// EPI 3: bf16 out + bias, TRANSPOSED into vt[4][1024 d][2048 s]:
//        vt[m0>>11][col][row%2048] = acc (ushort4 per fragment).
// Stage plan per iter j (buf0=2j, buf1=2j+1): S1=p1:buf1.A1(+64)
//   S2=p2:buf0.{A0,B0}(+128) S3=p3:buf0.A1(+128) S4=p4:buf1.{A0,B0}(+192)
// Reads (for NEXT phase): p1:aB<-buf0.A1[S3(j-1)] p2:aA<-buf1.A0,b1<-
//   buf1.B0[S4(j-1)] p3:aB<-buf1.A1[S1(j)] p4:aA<-buf0.A0,b0<-buf0.B0[S2(j)]
// vmcnt per phase end: p1:2 (retires S4(j-1)) p2:4 (S1) p3:2 (S2) p4:4 (S3).
// Requires: M%256==0, N%128==0, K%128==0, (gx*gy)%8==0.
template<int EPI>
__global__ __launch_bounds__(512, 2) void gemm256n128(
    const u16* __restrict__ Ap, long lda, long aBatch,
    const u16* __restrict__ Bp, long ldb, long bBatch,
    void* __restrict__ Cp, long ldc, long cBatch,
    const float* __restrict__ bias,
    float scale, int K)
{
    // 2 bufs x (A[256][64] + B[128][64]) bf16 = 2 x 48 KB = 96 KB.
    __shared__ __attribute__((aligned(16))) u16 lds[49152];

    const int tid  = threadIdx.x;
    const int lane = tid & 63;
    const int wave = tid >> 6;          // 0..7
    const int wrq  = wave >> 1;         // 0..3: 32-row band within quadrant
    const int wcq  = wave & 1;          // 0..1: 64-col band within 128 cols
    const int m16  = lane & 15;
    const int quad = lane >> 4;
    const int b    = blockIdx.z;

    const int gx = gridDim.x;
    const int flat = xcd_swz(blockIdx.y * gx + blockIdx.x, gx * gridDim.y);
    const long m0  = (long)(flat / gx) * 256;
    const long n0  = (long)(flat % gx) * 128;

    const u16* A = Ap + (long)b * aBatch;
    const u16* B = Bp + (long)b * bBatch;

    const int srow   = lane >> 3;
    const int schunk = (lane & 7) ^ srow;
    const u16* aP = A + (m0 + wave * 8 + srow) * lda + schunk * 8;
    const u16* bP = B + (n0 + wave * 8 + srow) * ldb + schunk * 8;

    const int cswz = (quad ^ (m16 & 7)) * 8;
    const int arow = wrq * 32 + m16;
    const int brow = wcq * 64 + m16;

    short8 aA[2][2], aB[2][2], b0[2][4], b1[2][4];
    f32x4 acc[2][2][4];                 // [qr][mi][ni]
    #pragma unroll
    for (int qr = 0; qr < 2; qr++)
        #pragma unroll
        for (int mi = 0; mi < 2; mi++)
            #pragma unroll
            for (int ni = 0; ni < 4; ni++)
                acc[qr][mi][ni] = (f32x4){0.f, 0.f, 0.f, 0.f};

    auto STAGE_A = [&](int buf, int h, int toff) {
        u16* l = (u16*)lds + buf * 24576 + h * 8192 + wave * 512;
        const u16* g = aP + (long)(h * 128) * lda + toff;
        gld16(l, g);
        gld16(l + 4096, g + (long)64 * lda);
    };
    auto STAGE_B = [&](int buf, int toff) {
        u16* l = (u16*)lds + buf * 24576 + 16384 + wave * 512;
        const u16* g = bP + toff;
        gld16(l, g);
        gld16(l + 4096, g + (long)64 * ldb);
    };
    auto RDA = [&](short8 (&d)[2][2], int buf, int qr) {
        const u16* p = (const u16*)lds + buf * 24576 + qr * 8192 + arow * 64;
        d[0][0] = *(const short8*)(p + cswz);
        d[0][1] = *(const short8*)(p + 1024 + cswz);
        d[1][0] = *(const short8*)(p + (cswz ^ 32));
        d[1][1] = *(const short8*)(p + 1024 + (cswz ^ 32));
    };
    auto RDB = [&](short8 (&d)[2][4], int buf) {
        const u16* p = (const u16*)lds + buf * 24576 + 16384 + brow * 64;
        #pragma unroll
        for (int ks = 0; ks < 2; ks++)
            #pragma unroll
            for (int ni = 0; ni < 4; ni++)
                d[ks][ni] = *(const short8*)(p + ni * 1024 + (cswz ^ (ks * 32)));
    };
    auto MMA = [&](f32x4 (&c)[2][4], const short8 (&a)[2][2],
                   const short8 (&bb)[2][4]) {
        __builtin_amdgcn_s_setprio(1);
        #pragma unroll
        for (int ks = 0; ks < 2; ks++)
            #pragma unroll
            for (int mi = 0; mi < 2; mi++)
                #pragma unroll
                for (int ni = 0; ni < 4; ni++)
                    c[mi][ni] = __builtin_amdgcn_mfma_f32_16x16x32_bf16(
                        a[ks][mi], bb[ks][ni], c[mi][ni], 0, 0, 0);
        __builtin_amdgcn_s_setprio(0);
    };

    const int nt = K >> 6;
    const int niter = nt >> 1;

    // prologue: FIFO = buf0.A0,B0 (4), buf0.A1 (2), buf1.A0,B0 (4).
    // vmcnt(4) retires buf0 entirely (pre-reads + p1's read).
    STAGE_A(0, 0, 0); STAGE_B(0, 0); STAGE_A(0, 1, 0);
    STAGE_A(1, 0, 64); STAGE_B(1, 64);
    asm volatile("s_waitcnt vmcnt(4)");
    __builtin_amdgcn_s_barrier();
    RDA(aA, 0, 0); RDB(b0, 0);

    #pragma unroll 1
    for (int j = 0; j < niter - 1; ++j) {
        // p1: buf0.q0 [aA,b0] ; read aB<-buf0.A1
        RDA(aB, 0, 1); STAGE_A(1, 1, 64);
        MMA(acc[0], aA, b0);
        asm volatile("s_waitcnt vmcnt(2)");
        __builtin_amdgcn_s_barrier();
        // p2: buf0.q1 [aB,b0] ; read aA<-buf1.A0, b1<-buf1.B
        RDA(aA, 1, 0); RDB(b1, 1); STAGE_A(0, 0, 128); STAGE_B(0, 128);
        MMA(acc[1], aB, b0);
        asm volatile("s_waitcnt vmcnt(4)");
        __builtin_amdgcn_s_barrier();
        // p3: buf1.q0 [aA,b1] ; read aB<-buf1.A1
        RDA(aB, 1, 1); STAGE_A(0, 1, 128);
        MMA(acc[0], aA, b1);
        asm volatile("s_waitcnt vmcnt(2)");
        __builtin_amdgcn_s_barrier();
        // p4: buf1.q1 [aB,b1] ; read aA<-buf0.A0, b0<-buf0.B (tile 2j+2)
        RDA(aA, 0, 0); RDB(b0, 0); STAGE_A(1, 0, 192); STAGE_B(1, 192);
        MMA(acc[1], aB, b1);
        asm volatile("s_waitcnt vmcnt(4)");
        __builtin_amdgcn_s_barrier();

        aP += 128; bP += 128;
    }

    // peeled final iteration (buf0=nt-2, buf1=nt-1): p1 stage real;
    // p2..p4 dead (clamped +64); p4's next-tile reads skipped.
    {
        RDA(aB, 0, 1); STAGE_A(1, 1, 64);
        MMA(acc[0], aA, b0);
        asm volatile("s_waitcnt vmcnt(2)");
        __builtin_amdgcn_s_barrier();
        RDA(aA, 1, 0); RDB(b1, 1); STAGE_A(0, 0, 64); STAGE_B(0, 64);
        MMA(acc[1], aB, b0);
        asm volatile("s_waitcnt vmcnt(4)");
        __builtin_amdgcn_s_barrier();
        RDA(aB, 1, 1); STAGE_A(0, 1, 64);
        MMA(acc[0], aA, b1);
        asm volatile("s_waitcnt vmcnt(2)");
        __builtin_amdgcn_s_barrier();
        MMA(acc[1], aB, b1);
    }

    // drain async LDS writes before epilogue/endpgm (LDS realloc hazard)
    asm volatile("s_waitcnt vmcnt(0)");

    // D mapping per 16x16 frag: col = lane&15, row = quad*4 + r.
    #pragma unroll
    for (int qr = 0; qr < 2; qr++) {
        const long row0 = m0 + qr * 128 + wrq * 32 + quad * 4;
        #pragma unroll
        for (int ni = 0; ni < 4; ni++) {
            const long col = n0 + wcq * 64 + ni * 16 + m16;
            if (EPI == 0) {
                u16* C = (u16*)Cp + (long)b * cBatch;
                const float bv = bias ? bias[col] : 0.f;
                #pragma unroll
                for (int mi = 0; mi < 2; mi++)
                    #pragma unroll
                    for (int r = 0; r < 4; r++)
                        C[(row0 + mi * 16 + r) * ldc + col] =
                            f2bf(acc[qr][mi][ni][r] + bv);
            } else if (EPI == 1) {
                u16* C = (u16*)Cp + (long)b * cBatch;
                #pragma unroll
                for (int mi = 0; mi < 2; mi++)
                    #pragma unroll
                    for (int r = 0; r < 4; r++)
                        C[(row0 + mi * 16 + r) * ldc + col] =
                            f2bf(acc[qr][mi][ni][r] * scale);
            } else if (EPI == 2) {
                float* C = (float*)Cp + (long)b * cBatch;
                const float bv = bias ? bias[col] : 0.f;
                #pragma unroll
                for (int mi = 0; mi < 2; mi++)
                    #pragma unroll
                    for (int r = 0; r < 4; r++)
                        C[(row0 + mi * 16 + r) * ldc + col] =
                            acc[qr][mi][ni][r] + bv;
            } else {
                // EPI 3: transposed V write. Cp = vt[4][1024][2048];
                // ldc = 2048 (s-stride), cBatch = 1024*2048. Blocks are
                // 256 rows, 2048%256==0 -> batch uniform per block.
                u16* C = (u16*)Cp + (m0 >> 11) * cBatch;
                const float bv = bias ? bias[col] : 0.f;
                #pragma unroll
                for (int mi = 0; mi < 2; mi++) {
                    const long sr = (row0 & 2047) + mi * 16;
                    us4 o;
                    #pragma unroll
                    for (int r = 0; r < 4; r++)
                        o[r] = f2bf(acc[qr][mi][ni][r] + bv);
                    *(us4*)(C + col * ldc + sr) = o;
                }
            }
        }
    }
}

// in-place masked row softmax over 2048 bf16 (f32 math). 1 block per row.
__global__ __launch_bounds__(256) void softmax2048(u16* __restrict__ S,
                                                   const int* __restrict__ mask) {
    const long row = blockIdx.x;
    u16* p = S + row * SEQ;
    const int* mrow = mask + row * SEQ;
    const int tid = threadIdx.x;

    short8 v = *(const short8*)(p + tid * 8);
    uint4 mw0 = *(const uint4*)(mrow + tid * 8);
    uint4 mw1 = *(const uint4*)(mrow + tid * 8 + 4);
    const unsigned int* mwv = (const unsigned int*)&mw0;

    float f[8];
    #pragma unroll
    for (int j = 0; j < 8; j++) {
        const unsigned int mv = (j < 4) ? mwv[j] : ((const unsigned int*)&mw1)[j - 4];
        f[j] = (mv == 0u) ? 1e-10f : bf2f((u16)v[j]);
    }

    float m = f[0];
    #pragma unroll
    for (int j = 1; j < 8; j++) m = fmaxf(m, f[j]);
    #pragma unroll
    for (int i = 1; i < 64; i <<= 1) m = fmaxf(m, __shfl_xor(m, i));

    __shared__ float redm[4], reds[4];
    if ((tid & 63) == 0) redm[tid >> 6] = m;
    __syncthreads();
    m = fmaxf(fmaxf(redm[0], redm[1]), fmaxf(redm[2], redm[3]));

    float e[8], s = 0.f;
    #pragma unroll
    for (int j = 0; j < 8; j++) { e[j] = __expf(f[j] - m); s += e[j]; }
    #pragma unroll
    for (int i = 1; i < 64; i <<= 1) s += __shfl_xor(s, i);
    if ((tid & 63) == 0) reds[tid >> 6] = s;
    __syncthreads();
    s = reds[0] + reds[1] + reds[2] + reds[3];

    const float inv = 1.f / s;
    short8 o;
    #pragma unroll
    for (int j = 0; j < 8; j++) o[j] = (short)f2bf(e[j] * inv);
    *(short8*)(p + tid * 8) = o;
}

extern "C" void kernel_launch(void* const* d_in, const int* in_sizes, int n_in,
                              void* d_out, int out_size, void* d_ws, size_t ws_size,
                              hipStream_t stream) {
    const float* x    = (const float*)d_in[0];
    const int*   mask = (const int*)d_in[1];
    const float* Wqkv = (const float*)d_in[2];
    const float* bqkv = (const float*)d_in[3];
    const float* Wout = (const float*)d_in[4];
    const float* bout = (const float*)d_in[5];
    float* out = (float*)d_out;

    char* ws = (char*)d_ws;
    // ws layout, total 102,760,448 bytes:
    //   [0,        16777216) xh  bf16 [8192][1024]          (cvt -> K1a/K1b)
    //   [16777216, 23068672) wqt bf16 [3072][1024]          (cvt -> K1a/K1b)
    //   [0,        33554432) sc  bf16 [4][2048][2048]       (K2 -> K4; xh,wqt dead)
    //   [33554432, 35651584) wot bf16 [1024][1024]          (cvt -> K5)
    //   [35651584, 69206016) qk  bf16 [8192][2048]          (K1a -> K2)
    //   [35651584, 52428800) attn bf16 [8192][1024]         (K4 -> K5; qk dead)
    //   [85983232,102760448) vt  bf16 [4][1024][2048]       (K1b -> K4)
    u16* xh   = (u16*)(ws + 0);
    u16* wqt  = (u16*)(ws + 16777216);
    u16* sc   = (u16*)(ws + 0);
    u16* wot  = (u16*)(ws + 33554432);
    u16* qk   = (u16*)(ws + 35651584);
    u16* attn = (u16*)(ws + 35651584);
    u16* vt   = (u16*)(ws + 85983232);

    cvt_bf16<<<4096, 256, 0, stream>>>(x, xh, 8388608);
    transpose_cvt<<<dim3(96, 32), 256, 0, stream>>>(Wqkv, wqt, 1024, 3072);
    transpose_cvt<<<dim3(32, 32), 256, 0, stream>>>(Wout, wot, 1024, 1024);

    // K1a: qk = x @ Wqkv[:, :2048] + bqkv[:2048]  (M=8192, N=2048, K=1024)
    //      16x32 = 512 blocks = 2.0 exact rounds
    gemm256n128<0><<<dim3(16, 32, 1), 512, 0, stream>>>(
        xh, 1024, 0, wqt, 1024, 0, qk, 2048, 0, bqkv, 1.f, 1024);

    // K1b: vt = (x @ Wqkv[:, 2048:] + bqkv[2048:])^T per batch
    //      (M=8192, N=1024, K=1024), transposed epilogue -> vt[b][d][s]
    //      8x32 = 256 blocks = 1.0 round (replaces old K1 V-cols +
    //      the entire transpose_v kernel)
    gemm256n128<3><<<dim3(8, 32, 1), 512, 0, stream>>>(
        xh, 1024, 0, wqt + (long)2048 * 1024, 1024, 0,
        vt, SEQ, (long)1024 * SEQ, bqkv + 2048, 1.f, 1024);

    // K2: sc[b] = (Q[b] @ K[b]^T)/32   (M=N=2048, K=1024), bf16 out
    //     A = qk cols 0-1023 (Q), B = qk cols 1024-2047 (K), lda=ldb=2048
    //     16x8x4 = 512 blocks = 2.0 exact rounds
    gemm256n128<1><<<dim3(16, 8, NB), 512, 0, stream>>>(
        qk, 2048, (long)SEQ * 2048, qk + 1024, 2048, (long)SEQ * 2048,
        sc, SEQ, (long)SEQ * SEQ, nullptr, 0.03125f, 1024);

    // K3: masked softmax rows (mask==0 -> 1e-10, f32 math, bf16 storage)
    softmax2048<<<dim3(NB * SEQ), 256, 0, stream>>>(sc, mask);

    // K4: attn[b] = P[b] @ V[b]   (M=2048, N=1024, K=2048), bf16 out
    //     8x8x4 = 256 blocks = 1.0 round
    gemm256n128<0><<<dim3(8, 8, NB), 512, 0, stream>>>(
        sc, SEQ, (long)SEQ * SEQ, vt, SEQ, (long)1024 * SEQ,
        attn, 1024, (long)SEQ * 1024, nullptr, 1.f, 2048);

    // K5: out = attn @ Wout + bout   (M=8192, N=1024, K=1024), f32 out
    //     8x32 = 256 blocks = 1.0 round
    gemm256n128<2><<<dim3(8, 32, 1), 512, 0, stream>>>(
        attn, 1024, 0, wot, 1024, 0, out, 1024, 0, bout, 1.f, 1024);
}

// Round 13
// 306.106 us; speedup vs baseline: 1.1170x; 1.0507x over previous
//
#include <hip/hip_runtime.h>

// Self-attention forward. Inputs f32: x[4,2048,1024], Wqkv[1024,3072],
// bqkv[3072], Wout[1024,1024], bout[1024]; mask[4,2048,2048] int32.
// Output f32 [4,2048,1024].
//
// Round-19: correctness-first bisect of the round-12 replay divergence.
//   GEMM pipeline reverted to the EXACT round-8 artifact (312us, passed,
//   clean counters): gemm256n128 4-phase read-ahead everywhere,
//   transpose_v reinstated, qkv[8192][3072] layout. The ONLY change kept
//   from round 12 is the prep fusion (cvt_bf16 + 2x transpose_cvt -> one
//   8192-block launch; pure elementwise/transpose, no async, no cross-
//   block deps -> race-free by construction). 9 -> 7 dispatches.
//   Outcome discriminates: pass@~290 => launch-overhead theory confirmed
//   AND round-12 bug localized to the fused gemm_k1; fail => prep is the
//   bug; pass@~312 => launch theory dead, round-8 stands.

typedef __attribute__((ext_vector_type(8))) short short8;
typedef __attribute__((ext_vector_type(4))) float f32x4;
typedef unsigned short u16;

#define SEQ 2048
#define NB 4

static __device__ __forceinline__ u16 f2bf(float f) {
    unsigned int u = __builtin_bit_cast(unsigned int, f);
    u += 0x7fffu + ((u >> 16) & 1u);   // RNE
    return (u16)(u >> 16);
}
static __device__ __forceinline__ float bf2f(u16 h) {
    unsigned int u = ((unsigned int)h) << 16;
    return __builtin_bit_cast(float, u);
}

// async global->LDS, 16 bytes/lane. LDS dest = wave-uniform base + lane*16.
static __device__ __forceinline__ void gld16(u16* l, const u16* g) {
    __builtin_amdgcn_global_load_lds(
        (__attribute__((address_space(1))) void*)(g),
        (__attribute__((address_space(3))) void*)(l),
        16, 0, 0);
}

// Fused preprocessing, one launch (block-uniform branch):
//   blocks [0,4096):    x f32 -> xh bf16 (8 elems/thread)
//   blocks [4096,7168): Wqkv [1024][3072] -> wqt [3072][1024] (T + cvt)
//   blocks [7168,8192): Wout [1024][1024] -> wot [1024][1024] (T + cvt)
__global__ __launch_bounds__(256) void prep(
    const float* __restrict__ x, u16* __restrict__ xh,
    const float* __restrict__ Wqkv, u16* __restrict__ wqt,
    const float* __restrict__ Wout, u16* __restrict__ wot)
{
    __shared__ float t[32][33];
    const int id  = blockIdx.x;
    const int tid = threadIdx.x;

    if (id < 4096) {
        const long i = ((long)id * 256 + tid) * 8;
        f32x4 a = *(const f32x4*)(x + i);
        f32x4 b = *(const f32x4*)(x + i + 4);
        short8 o;
        o[0] = (short)f2bf(a.x); o[1] = (short)f2bf(a.y);
        o[2] = (short)f2bf(a.z); o[3] = (short)f2bf(a.w);
        o[4] = (short)f2bf(b.x); o[5] = (short)f2bf(b.y);
        o[6] = (short)f2bf(b.z); o[7] = (short)f2bf(b.w);
        *(short8*)(xh + i) = o;
        return;
    }

    const float* in; u16* out; int C, bx, by;
    if (id < 7168) { const int k = id - 4096; in = Wqkv; out = wqt; C = 3072; bx = k % 96; by = k / 96; }
    else           { const int k = id - 7168; in = Wout; out = wot; C = 1024; bx = k % 32; by = k / 32; }
    const int c0 = bx * 32;
    const int r0 = by * 32;
    const int xx = tid & 31;
    const int yy = (tid >> 5) * 4;
    #pragma unroll
    for (int i = 0; i < 4; i++)
        t[yy + i][xx] = in[(long)(r0 + yy + i) * C + c0 + xx];
    __syncthreads();
    #pragma unroll
    for (int i = 0; i < 4; i++)
        out[(long)(c0 + yy + i) * 1024 + r0 + xx] = f2bf(t[xx][yy + i]);
}

// V slice of qkv -> vt [b][1024 d][2048 s]. bf16 32x32 tile transpose.
__global__ __launch_bounds__(256) void transpose_v(const u16* __restrict__ qkv,
                                                   u16* __restrict__ vt) {
    __shared__ u16 t[32][33];
    const int b = blockIdx.z;
    const int s0 = blockIdx.y * 32;
    const int d0 = blockIdx.x * 32;
    const int x = threadIdx.x & 31;
    const int y = (threadIdx.x >> 5) * 4;
    const u16* src = qkv + (long)b * SEQ * 3072 + 2048;
    u16* dst = vt + (long)b * 1024 * SEQ;
    #pragma unroll
    for (int i = 0; i < 4; i++)
        t[y + i][x] = src[(long)(s0 + y + i) * 3072 + d0 + x];
    __syncthreads();
    #pragma unroll
    for (int i = 0; i < 4; i++)
        dst[(long)(d0 + y + i) * SEQ + s0 + x] = t[x][y + i];
}

// bijective XCD swizzle of the flat (y*gx+x) tile id; requires nwg%8==0.
static __device__ __forceinline__ int xcd_swz(int flat, int nwg) {
    return (flat & 7) * (nwg >> 3) + (flat >> 3);
}

// bf16 MFMA GEMM, 256x128 tile, 4-phase 2-buffer read-ahead pipeline
// (round-8 schedule, harness-verified at 312us total).
// C[m][n] = sum_k A[m][k] * Bt[n][k]   (Bt = B^T, [N][K] row-major).
// EPI 0: bf16 out + optional f32 bias.  EPI 1: bf16 out, *scale.
// EPI 2: f32 out + f32 bias.
// Stage plan per iter j (buf0=2j, buf1=2j+1): S1=p1:buf1.A1(+64)
//   S2=p2:buf0.{A0,B0}(+128) S3=p3:buf0.A1(+128) S4=p4:buf1.{A0,B0}(+192)
// Reads (for NEXT phase): p1:aB<-buf0.A1[S3(j-1)] p2:aA<-buf1.A0,b1<-
//   buf1.B0[S4(j-1)] p3:aB<-buf1.A1[S1(j)] p4:aA<-buf0.A0,b0<-buf0.B0[S2(j)]
// vmcnt per phase end: p1:2 (retires S4(j-1)) p2:4 (S1) p3:2 (S2) p4:4 (S3).
// Requires: M%256==0, N%128==0, K%128==0, (gx*gy)%8==0.
template<int EPI>
__global__ __launch_bounds__(512, 2) void gemm256n128(
    const u16* __restrict__ Ap, long lda, long aBatch,
    const u16* __restrict__ Bp, long ldb, long bBatch,
    void* __restrict__ Cp, long ldc, long cBatch,
    const float* __restrict__ bias,
    float scale, int K)
{
    // 2 bufs x (A[256][64] + B[128][64]) bf16 = 2 x 48 KB = 96 KB.
    __shared__ __attribute__((aligned(16))) u16 lds[49152];

    const int tid  = threadIdx.x;
    const int lane = tid & 63;
    const int wave = tid >> 6;          // 0..7
    const int wrq  = wave >> 1;         // 0..3: 32-row band within quadrant
    const int wcq  = wave & 1;          // 0..1: 64-col band within 128 cols
    const int m16  = lane & 15;
    const int quad = lane >> 4;
    const int b    = blockIdx.z;

    const int gx = gridDim.x;
    const int flat = xcd_swz(blockIdx.y * gx + blockIdx.x, gx * gridDim.y);
    const long m0  = (long)(flat / gx) * 256;
    const long n0  = (long)(flat % gx) * 128;

    const u16* A = Ap + (long)b * aBatch;
    const u16* B = Bp + (long)b * bBatch;

    const int srow   = lane >> 3;
    const int schunk = (lane & 7) ^ srow;
    const u16* aP = A + (m0 + wave * 8 + srow) * lda + schunk * 8;
    const u16* bP = B + (n0 + wave * 8 + srow) * ldb + schunk * 8;

    const int cswz = (quad ^ (m16 & 7)) * 8;
    const int arow = wrq * 32 + m16;
    const int brow = wcq * 64 + m16;

    short8 aA[2][2], aB[2][2], b0[2][4], b1[2][4];
    f32x4 acc[2][2][4];                 // [qr][mi][ni]
    #pragma unroll
    for (int qr = 0; qr < 2; qr++)
        #pragma unroll
        for (int mi = 0; mi < 2; mi++)
            #pragma unroll
            for (int ni = 0; ni < 4; ni++)
                acc[qr][mi][ni] = (f32x4){0.f, 0.f, 0.f, 0.f};

    auto STAGE_A = [&](int buf, int h, int toff) {
        u16* l = (u16*)lds + buf * 24576 + h * 8192 + wave * 512;
        const u16* g = aP + (long)(h * 128) * lda + toff;
        gld16(l, g);
        gld16(l + 4096, g + (long)64 * lda);
    };
    auto STAGE_B = [&](int buf, int toff) {
        u16* l = (u16*)lds + buf * 24576 + 16384 + wave * 512;
        const u16* g = bP + toff;
        gld16(l, g);
        gld16(l + 4096, g + (long)64 * ldb);
    };
    auto RDA = [&](short8 (&d)[2][2], int buf, int qr) {
        const u16* p = (const u16*)lds + buf * 24576 + qr * 8192 + arow * 64;
        d[0][0] = *(const short8*)(p + cswz);
        d[0][1] = *(const short8*)(p + 1024 + cswz);
        d[1][0] = *(const short8*)(p + (cswz ^ 32));
        d[1][1] = *(const short8*)(p + 1024 + (cswz ^ 32));
    };
    auto RDB = [&](short8 (&d)[2][4], int buf) {
        const u16* p = (const u16*)lds + buf * 24576 + 16384 + brow * 64;
        #pragma unroll
        for (int ks = 0; ks < 2; ks++)
            #pragma unroll
            for (int ni = 0; ni < 4; ni++)
                d[ks][ni] = *(const short8*)(p + ni * 1024 + (cswz ^ (ks * 32)));
    };
    auto MMA = [&](f32x4 (&c)[2][4], const short8 (&a)[2][2],
                   const short8 (&bb)[2][4]) {
        __builtin_amdgcn_s_setprio(1);
        #pragma unroll
        for (int ks = 0; ks < 2; ks++)
            #pragma unroll
            for (int mi = 0; mi < 2; mi++)
                #pragma unroll
                for (int ni = 0; ni < 4; ni++)
                    c[mi][ni] = __builtin_amdgcn_mfma_f32_16x16x32_bf16(
                        a[ks][mi], bb[ks][ni], c[mi][ni], 0, 0, 0);
        __builtin_amdgcn_s_setprio(0);
    };

    const int nt = K >> 6;
    const int niter = nt >> 1;

    // prologue: FIFO = buf0.A0,B0 (4), buf0.A1 (2), buf1.A0,B0 (4).
    // vmcnt(4) retires buf0 entirely (pre-reads + p1's read).
    STAGE_A(0, 0, 0); STAGE_B(0, 0); STAGE_A(0, 1, 0);
    STAGE_A(1, 0, 64); STAGE_B(1, 64);
    asm volatile("s_waitcnt vmcnt(4)");
    __builtin_amdgcn_s_barrier();
    RDA(aA, 0, 0); RDB(b0, 0);

    #pragma unroll 1
    for (int j = 0; j < niter - 1; ++j) {
        // p1: buf0.q0 [aA,b0] ; read aB<-buf0.A1
        RDA(aB, 0, 1); STAGE_A(1, 1, 64);
        MMA(acc[0], aA, b0);
        asm volatile("s_waitcnt vmcnt(2)");
        __builtin_amdgcn_s_barrier();
        // p2: buf0.q1 [aB,b0] ; read aA<-buf1.A0, b1<-buf1.B
        RDA(aA, 1, 0); RDB(b1, 1); STAGE_A(0, 0, 128); STAGE_B(0, 128);
        MMA(acc[1], aB, b0);
        asm volatile("s_waitcnt vmcnt(4)");
        __builtin_amdgcn_s_barrier();
        // p3: buf1.q0 [aA,b1] ; read aB<-buf1.A1
        RDA(aB, 1, 1); STAGE_A(0, 1, 128);
        MMA(acc[0], aA, b1);
        asm volatile("s_waitcnt vmcnt(2)");
        __builtin_amdgcn_s_barrier();
        // p4: buf1.q1 [aB,b1] ; read aA<-buf0.A0, b0<-buf0.B (tile 2j+2)
        RDA(aA, 0, 0); RDB(b0, 0); STAGE_A(1, 0, 192); STAGE_B(1, 192);
        MMA(acc[1], aB, b1);
        asm volatile("s_waitcnt vmcnt(4)");
        __builtin_amdgcn_s_barrier();

        aP += 128; bP += 128;
    }

    // peeled final iteration (buf0=nt-2, buf1=nt-1): p1 stage real;
    // p2..p4 dead (clamped +64); p4's next-tile reads skipped.
    {
        RDA(aB, 0, 1); STAGE_A(1, 1, 64);
        MMA(acc[0], aA, b0);
        asm volatile("s_waitcnt vmcnt(2)");
        __builtin_amdgcn_s_barrier();
        RDA(aA, 1, 0); RDB(b1, 1); STAGE_A(0, 0, 64); STAGE_B(0, 64);
        MMA(acc[1], aB, b0);
        asm volatile("s_waitcnt vmcnt(4)");
        __builtin_amdgcn_s_barrier();
        RDA(aB, 1, 1); STAGE_A(0, 1, 64);
        MMA(acc[0], aA, b1);
        asm volatile("s_waitcnt vmcnt(2)");
        __builtin_amdgcn_s_barrier();
        MMA(acc[1], aB, b1);
    }

    // drain async LDS writes before epilogue/endpgm (LDS realloc hazard)
    asm volatile("s_waitcnt vmcnt(0)");

    // D mapping per 16x16 frag: col = lane&15, row = quad*4 + r.
    #pragma unroll
    for (int qr = 0; qr < 2; qr++) {
        const long row0 = m0 + qr * 128 + wrq * 32 + quad * 4;
        #pragma unroll
        for (int ni = 0; ni < 4; ni++) {
            const long col = n0 + wcq * 64 + ni * 16 + m16;
            if (EPI == 0) {
                u16* C = (u16*)Cp + (long)b * cBatch;
                const float bv = bias ? bias[col] : 0.f;
                #pragma unroll
                for (int mi = 0; mi < 2; mi++)
                    #pragma unroll
                    for (int r = 0; r < 4; r++)
                        C[(row0 + mi * 16 + r) * ldc + col] =
                            f2bf(acc[qr][mi][ni][r] + bv);
            } else if (EPI == 1) {
                u16* C = (u16*)Cp + (long)b * cBatch;
                #pragma unroll
                for (int mi = 0; mi < 2; mi++)
                    #pragma unroll
                    for (int r = 0; r < 4; r++)
                        C[(row0 + mi * 16 + r) * ldc + col] =
                            f2bf(acc[qr][mi][ni][r] * scale);
            } else {
                float* C = (float*)Cp + (long)b * cBatch;
                const float bv = bias ? bias[col] : 0.f;
                #pragma unroll
                for (int mi = 0; mi < 2; mi++)
                    #pragma unroll
                    for (int r = 0; r < 4; r++)
                        C[(row0 + mi * 16 + r) * ldc + col] =
                            acc[qr][mi][ni][r] + bv;
            }
        }
    }
}

// in-place masked row softmax over 2048 bf16 (f32 math). 1 block per row.
__global__ __launch_bounds__(256) void softmax2048(u16* __restrict__ S,
                                                   const int* __restrict__ mask) {
    const long row = blockIdx.x;
    u16* p = S + row * SEQ;
    const int* mrow = mask + row * SEQ;
    const int tid = threadIdx.x;

    short8 v = *(const short8*)(p + tid * 8);
    uint4 mw0 = *(const uint4*)(mrow + tid * 8);
    uint4 mw1 = *(const uint4*)(mrow + tid * 8 + 4);
    const unsigned int* mwv = (const unsigned int*)&mw0;

    float f[8];
    #pragma unroll
    for (int j = 0; j < 8; j++) {
        const unsigned int mv = (j < 4) ? mwv[j] : ((const unsigned int*)&mw1)[j - 4];
        f[j] = (mv == 0u) ? 1e-10f : bf2f((u16)v[j]);
    }

    float m = f[0];
    #pragma unroll
    for (int j = 1; j < 8; j++) m = fmaxf(m, f[j]);
    #pragma unroll
    for (int i = 1; i < 64; i <<= 1) m = fmaxf(m, __shfl_xor(m, i));

    __shared__ float redm[4], reds[4];
    if ((tid & 63) == 0) redm[tid >> 6] = m;
    __syncthreads();
    m = fmaxf(fmaxf(redm[0], redm[1]), fmaxf(redm[2], redm[3]));

    float e[8], s = 0.f;
    #pragma unroll
    for (int j = 0; j < 8; j++) { e[j] = __expf(f[j] - m); s += e[j]; }
    #pragma unroll
    for (int i = 1; i < 64; i <<= 1) s += __shfl_xor(s, i);
    if ((tid & 63) == 0) reds[tid >> 6] = s;
    __syncthreads();
    s = reds[0] + reds[1] + reds[2] + reds[3];

    const float inv = 1.f / s;
    short8 o;
    #pragma unroll
    for (int j = 0; j < 8; j++) o[j] = (short)f2bf(e[j] * inv);
    *(short8*)(p + tid * 8) = o;
}

extern "C" void kernel_launch(void* const* d_in, const int* in_sizes, int n_in,
                              void* d_out, int out_size, void* d_ws, size_t ws_size,
                              hipStream_t stream) {
    const float* x    = (const float*)d_in[0];
    const int*   mask = (const int*)d_in[1];
    const float* Wqkv = (const float*)d_in[2];
    const float* bqkv = (const float*)d_in[3];
    const float* Wout = (const float*)d_in[4];
    const float* bout = (const float*)d_in[5];
    float* out = (float*)d_out;

    char* ws = (char*)d_ws;
    // ws layout, total 102,760,448 bytes (round-8 layout):
    //   [0,        16777216) xh  bf16 [8192][1024]          (prep -> K1)
    //   [16777216, 23068672) wqt bf16 [3072][1024]          (prep -> K1)
    //   [0,        33554432) sc  bf16 [4][2048][2048]       (K2 -> K4; xh,wqt dead)
    //   [33554432, 35651584) wot bf16 [1024][1024]          (prep -> K5)
    //   [35651584, 85983232) qkv bf16 [8192][3072]          (K1 -> K2, tv)
    //   [35651584, 52428800) attn bf16 [8192][1024]         (K4 -> K5; qkv dead)
    //   [85983232,102760448) vt  bf16 [4][1024][2048]       (tv -> K4)
    u16* xh   = (u16*)(ws + 0);
    u16* wqt  = (u16*)(ws + 16777216);
    u16* sc   = (u16*)(ws + 0);
    u16* wot  = (u16*)(ws + 33554432);
    u16* qkv  = (u16*)(ws + 35651584);
    u16* attn = (u16*)(ws + 35651584);
    u16* vt   = (u16*)(ws + 85983232);

    // P: all input conversions/transposes, one launch (8192 blocks)
    prep<<<dim3(8192), 256, 0, stream>>>(x, xh, Wqkv, wqt, Wout, wot);

    // K1: qkv = x @ Wqkv + bqkv   (M=8192, N=3072, K=1024), bf16 out
    //     24x32 = 768 blocks = 3.0 exact rounds
    gemm256n128<0><<<dim3(24, 32, 1), 512, 0, stream>>>(
        xh, 1024, 0, wqt, 1024, 0, qkv, 3072, 0, bqkv, 1.f, 1024);

    // V slice -> vt [b][d][s]
    transpose_v<<<dim3(32, 64, NB), 256, 0, stream>>>(qkv, vt);

    // K2: sc[b] = (Q[b] @ K[b]^T)/32   (M=N=2048, K=1024), bf16 out
    //     16x8x4 = 512 blocks = 2.0 exact rounds
    gemm256n128<1><<<dim3(16, 8, NB), 512, 0, stream>>>(
        qkv, 3072, (long)SEQ * 3072, qkv + 1024, 3072, (long)SEQ * 3072,
        sc, SEQ, (long)SEQ * SEQ, nullptr, 0.03125f, 1024);

    // K3: masked softmax rows (mask==0 -> 1e-10, f32 math, bf16 storage)
    softmax2048<<<dim3(NB * SEQ), 256, 0, stream>>>(sc, mask);

    // K4: attn[b] = P[b] @ V[b]   (M=2048, N=1024, K=2048), bf16 out
    //     8x8x4 = 256 blocks = 1.0 round
    gemm256n128<0><<<dim3(8, 8, NB), 512, 0, stream>>>(
        sc, SEQ, (long)SEQ * SEQ, vt, SEQ, (long)1024 * SEQ,
        attn, 1024, (long)SEQ * 1024, nullptr, 1.f, 2048);

    // K5: out = attn @ Wout + bout   (M=8192, N=1024, K=1024), f32 out
    //     8x32 = 256 blocks = 1.0 round
    gemm256n128<2><<<dim3(8, 32, 1), 512, 0, stream>>>(
        attn, 1024, 0, wot, 1024, 0, out, 1024, 0, bout, 1.f, 1024);
}

// Round 14
// 299.291 us; speedup vs baseline: 1.1424x; 1.0228x over previous
//
#include <hip/hip_runtime.h>

// Self-attention forward. Inputs f32: x[4,2048,1024], Wqkv[1024,3072],
// bqkv[3072], Wout[1024,1024], bout[1024]; mask[4,2048,2048] int32.
// Output f32 [4,2048,1024].
//
// Round-20: union of two harness-PASSED configurations (no new code):
//   - prep fusion from round 13 (306us, passed): cvt_bf16 + 2x
//     transpose_cvt in one 8192-block launch.
//   - K1a/K1b split from round 11 (321us, passed): K1a -> tight
//     qk[8192][2048] (EPI0, 512 blocks = 2.0 rounds); K1b -> vt via
//     transposed EPI3 epilogue (256 blocks = 1.0 round). Eliminates
//     transpose_v's 33.5 MB LDS round-trip; K2 lda/ldb tighten to 2048.
//   7 launches (same as round 13); K1-class kernel time 81 -> ~69us.
//   GEMM core = round-8 4-phase read-ahead schedule, unchanged.

typedef __attribute__((ext_vector_type(8))) short short8;
typedef __attribute__((ext_vector_type(4))) float f32x4;
typedef __attribute__((ext_vector_type(4))) unsigned short us4;
typedef unsigned short u16;

#define SEQ 2048
#define NB 4

static __device__ __forceinline__ u16 f2bf(float f) {
    unsigned int u = __builtin_bit_cast(unsigned int, f);
    u += 0x7fffu + ((u >> 16) & 1u);   // RNE
    return (u16)(u >> 16);
}
static __device__ __forceinline__ float bf2f(u16 h) {
    unsigned int u = ((unsigned int)h) << 16;
    return __builtin_bit_cast(float, u);
}

// async global->LDS, 16 bytes/lane. LDS dest = wave-uniform base + lane*16.
static __device__ __forceinline__ void gld16(u16* l, const u16* g) {
    __builtin_amdgcn_global_load_lds(
        (__attribute__((address_space(1))) void*)(g),
        (__attribute__((address_space(3))) void*)(l),
        16, 0, 0);
}

// Fused preprocessing, one launch (block-uniform branch):
//   blocks [0,4096):    x f32 -> xh bf16 (8 elems/thread)
//   blocks [4096,7168): Wqkv [1024][3072] -> wqt [3072][1024] (T + cvt)
//   blocks [7168,8192): Wout [1024][1024] -> wot [1024][1024] (T + cvt)
__global__ __launch_bounds__(256) void prep(
    const float* __restrict__ x, u16* __restrict__ xh,
    const float* __restrict__ Wqkv, u16* __restrict__ wqt,
    const float* __restrict__ Wout, u16* __restrict__ wot)
{
    __shared__ float t[32][33];
    const int id  = blockIdx.x;
    const int tid = threadIdx.x;

    if (id < 4096) {
        const long i = ((long)id * 256 + tid) * 8;
        f32x4 a = *(const f32x4*)(x + i);
        f32x4 b = *(const f32x4*)(x + i + 4);
        short8 o;
        o[0] = (short)f2bf(a.x); o[1] = (short)f2bf(a.y);
        o[2] = (short)f2bf(a.z); o[3] = (short)f2bf(a.w);
        o[4] = (short)f2bf(b.x); o[5] = (short)f2bf(b.y);
        o[6] = (short)f2bf(b.z); o[7] = (short)f2bf(b.w);
        *(short8*)(xh + i) = o;
        return;
    }

    const float* in; u16* out; int C, bx, by;
    if (id < 7168) { const int k = id - 4096; in = Wqkv; out = wqt; C = 3072; bx = k % 96; by = k / 96; }
    else           { const int k = id - 7168; in = Wout; out = wot; C = 1024; bx = k % 32; by = k / 32; }
    const int c0 = bx * 32;
    const int r0 = by * 32;
    const int xx = tid & 31;
    const int yy = (tid >> 5) * 4;
    #pragma unroll
    for (int i = 0; i < 4; i++)
        t[yy + i][xx] = in[(long)(r0 + yy + i) * C + c0 + xx];
    __syncthreads();
    #pragma unroll
    for (int i = 0; i < 4; i++)
        out[(long)(c0 + yy + i) * 1024 + r0 + xx] = f2bf(t[xx][yy + i]);
}

// bijective XCD swizzle of the flat (y*gx+x) tile id; requires nwg%8==0.
static __device__ __forceinline__ int xcd_swz(int flat, int nwg) {
    return (flat & 7) * (nwg >> 3) + (flat >> 3);
}

// bf16 MFMA GEMM, 256x128 tile, 4-phase 2-buffer read-ahead pipeline
// (round-8 schedule, harness-verified).
// C[m][n] = sum_k A[m][k] * Bt[n][k]   (Bt = B^T, [N][K] row-major).
// EPI 0: bf16 out + optional f32 bias.  EPI 1: bf16 out, *scale.
// EPI 2: f32 out + f32 bias.
// EPI 3: bf16 out + bias, TRANSPOSED into vt[4][1024 d][2048 s]:
//        vt[m0>>11][col][row%2048] = acc (ushort4 per fragment).
//        (harness-verified in round 11.)
// Stage plan per iter j (buf0=2j, buf1=2j+1): S1=p1:buf1.A1(+64)
//   S2=p2:buf0.{A0,B0}(+128) S3=p3:buf0.A1(+128) S4=p4:buf1.{A0,B0}(+192)
// Reads (for NEXT phase): p1:aB<-buf0.A1[S3(j-1)] p2:aA<-buf1.A0,b1<-
//   buf1.B0[S4(j-1)] p3:aB<-buf1.A1[S1(j)] p4:aA<-buf0.A0,b0<-buf0.B0[S2(j)]
// vmcnt per phase end: p1:2 (retires S4(j-1)) p2:4 (S1) p3:2 (S2) p4:4 (S3).
// Requires: M%256==0, N%128==0, K%128==0, (gx*gy)%8==0.
template<int EPI>
__global__ __launch_bounds__(512, 2) void gemm256n128(
    const u16* __restrict__ Ap, long lda, long aBatch,
    const u16* __restrict__ Bp, long ldb, long bBatch,
    void* __restrict__ Cp, long ldc, long cBatch,
    const float* __restrict__ bias,
    float scale, int K)
{
    // 2 bufs x (A[256][64] + B[128][64]) bf16 = 2 x 48 KB = 96 KB.
    __shared__ __attribute__((aligned(16))) u16 lds[49152];

    const int tid  = threadIdx.x;
    const int lane = tid & 63;
    const int wave = tid >> 6;          // 0..7
    const int wrq  = wave >> 1;         // 0..3: 32-row band within quadrant
    const int wcq  = wave & 1;          // 0..1: 64-col band within 128 cols
    const int m16  = lane & 15;
    const int quad = lane >> 4;
    const int b    = blockIdx.z;

    const int gx = gridDim.x;
    const int flat = xcd_swz(blockIdx.y * gx + blockIdx.x, gx * gridDim.y);
    const long m0  = (long)(flat / gx) * 256;
    const long n0  = (long)(flat % gx) * 128;

    const u16* A = Ap + (long)b * aBatch;
    const u16* B = Bp + (long)b * bBatch;

    const int srow   = lane >> 3;
    const int schunk = (lane & 7) ^ srow;
    const u16* aP = A + (m0 + wave * 8 + srow) * lda + schunk * 8;
    const u16* bP = B + (n0 + wave * 8 + srow) * ldb + schunk * 8;

    const int cswz = (quad ^ (m16 & 7)) * 8;
    const int arow = wrq * 32 + m16;
    const int brow = wcq * 64 + m16;

    short8 aA[2][2], aB[2][2], b0[2][4], b1[2][4];
    f32x4 acc[2][2][4];                 // [qr][mi][ni]
    #pragma unroll
    for (int qr = 0; qr < 2; qr++)
        #pragma unroll
        for (int mi = 0; mi < 2; mi++)
            #pragma unroll
            for (int ni = 0; ni < 4; ni++)
                acc[qr][mi][ni] = (f32x4){0.f, 0.f, 0.f, 0.f};

    auto STAGE_A = [&](int buf, int h, int toff) {
        u16* l = (u16*)lds + buf * 24576 + h * 8192 + wave * 512;
        const u16* g = aP + (long)(h * 128) * lda + toff;
        gld16(l, g);
        gld16(l + 4096, g + (long)64 * lda);
    };
    auto STAGE_B = [&](int buf, int toff) {
        u16* l = (u16*)lds + buf * 24576 + 16384 + wave * 512;
        const u16* g = bP + toff;
        gld16(l, g);
        gld16(l + 4096, g + (long)64 * ldb);
    };
    auto RDA = [&](short8 (&d)[2][2], int buf, int qr) {
        const u16* p = (const u16*)lds + buf * 24576 + qr * 8192 + arow * 64;
        d[0][0] = *(const short8*)(p + cswz);
        d[0][1] = *(const short8*)(p + 1024 + cswz);
        d[1][0] = *(const short8*)(p + (cswz ^ 32));
        d[1][1] = *(const short8*)(p + 1024 + (cswz ^ 32));
    };
    auto RDB = [&](short8 (&d)[2][4], int buf) {
        const u16* p = (const u16*)lds + buf * 24576 + 16384 + brow * 64;
        #pragma unroll
        for (int ks = 0; ks < 2; ks++)
            #pragma unroll
            for (int ni = 0; ni < 4; ni++)
                d[ks][ni] = *(const short8*)(p + ni * 1024 + (cswz ^ (ks * 32)));
    };
    auto MMA = [&](f32x4 (&c)[2][4], const short8 (&a)[2][2],
                   const short8 (&bb)[2][4]) {
        __builtin_amdgcn_s_setprio(1);
        #pragma unroll
        for (int ks = 0; ks < 2; ks++)
            #pragma unroll
            for (int mi = 0; mi < 2; mi++)
                #pragma unroll
                for (int ni = 0; ni < 4; ni++)
                    c[mi][ni] = __builtin_amdgcn_mfma_f32_16x16x32_bf16(
                        a[ks][mi], bb[ks][ni], c[mi][ni], 0, 0, 0);
        __builtin_amdgcn_s_setprio(0);
    };

    const int nt = K >> 6;
    const int niter = nt >> 1;

    // prologue: FIFO = buf0.A0,B0 (4), buf0.A1 (2), buf1.A0,B0 (4).
    // vmcnt(4) retires buf0 entirely (pre-reads + p1's read).
    STAGE_A(0, 0, 0); STAGE_B(0, 0); STAGE_A(0, 1, 0);
    STAGE_A(1, 0, 64); STAGE_B(1, 64);
    asm volatile("s_waitcnt vmcnt(4)");
    __builtin_amdgcn_s_barrier();
    RDA(aA, 0, 0); RDB(b0, 0);

    #pragma unroll 1
    for (int j = 0; j < niter - 1; ++j) {
        // p1: buf0.q0 [aA,b0] ; read aB<-buf0.A1
        RDA(aB, 0, 1); STAGE_A(1, 1, 64);
        MMA(acc[0], aA, b0);
        asm volatile("s_waitcnt vmcnt(2)");
        __builtin_amdgcn_s_barrier();
        // p2: buf0.q1 [aB,b0] ; read aA<-buf1.A0, b1<-buf1.B
        RDA(aA, 1, 0); RDB(b1, 1); STAGE_A(0, 0, 128); STAGE_B(0, 128);
        MMA(acc[1], aB, b0);
        asm volatile("s_waitcnt vmcnt(4)");
        __builtin_amdgcn_s_barrier();
        // p3: buf1.q0 [aA,b1] ; read aB<-buf1.A1
        RDA(aB, 1, 1); STAGE_A(0, 1, 128);
        MMA(acc[0], aA, b1);
        asm volatile("s_waitcnt vmcnt(2)");
        __builtin_amdgcn_s_barrier();
        // p4: buf1.q1 [aB,b1] ; read aA<-buf0.A0, b0<-buf0.B (tile 2j+2)
        RDA(aA, 0, 0); RDB(b0, 0); STAGE_A(1, 0, 192); STAGE_B(1, 192);
        MMA(acc[1], aB, b1);
        asm volatile("s_waitcnt vmcnt(4)");
        __builtin_amdgcn_s_barrier();

        aP += 128; bP += 128;
    }

    // peeled final iteration (buf0=nt-2, buf1=nt-1): p1 stage real;
    // p2..p4 dead (clamped +64); p4's next-tile reads skipped.
    {
        RDA(aB, 0, 1); STAGE_A(1, 1, 64);
        MMA(acc[0], aA, b0);
        asm volatile("s_waitcnt vmcnt(2)");
        __builtin_amdgcn_s_barrier();
        RDA(aA, 1, 0); RDB(b1, 1); STAGE_A(0, 0, 64); STAGE_B(0, 64);
        MMA(acc[1], aB, b0);
        asm volatile("s_waitcnt vmcnt(4)");
        __builtin_amdgcn_s_barrier();
        RDA(aB, 1, 1); STAGE_A(0, 1, 64);
        MMA(acc[0], aA, b1);
        asm volatile("s_waitcnt vmcnt(2)");
        __builtin_amdgcn_s_barrier();
        MMA(acc[1], aB, b1);
    }

    // drain async LDS writes before epilogue/endpgm (LDS realloc hazard)
    asm volatile("s_waitcnt vmcnt(0)");

    // D mapping per 16x16 frag: col = lane&15, row = quad*4 + r.
    #pragma unroll
    for (int qr = 0; qr < 2; qr++) {
        const long row0 = m0 + qr * 128 + wrq * 32 + quad * 4;
        #pragma unroll
        for (int ni = 0; ni < 4; ni++) {
            const long col = n0 + wcq * 64 + ni * 16 + m16;
            if (EPI == 0) {
                u16* C = (u16*)Cp + (long)b * cBatch;
                const float bv = bias ? bias[col] : 0.f;
                #pragma unroll
                for (int mi = 0; mi < 2; mi++)
                    #pragma unroll
                    for (int r = 0; r < 4; r++)
                        C[(row0 + mi * 16 + r) * ldc + col] =
                            f2bf(acc[qr][mi][ni][r] + bv);
            } else if (EPI == 1) {
                u16* C = (u16*)Cp + (long)b * cBatch;
                #pragma unroll
                for (int mi = 0; mi < 2; mi++)
                    #pragma unroll
                    for (int r = 0; r < 4; r++)
                        C[(row0 + mi * 16 + r) * ldc + col] =
                            f2bf(acc[qr][mi][ni][r] * scale);
            } else if (EPI == 2) {
                float* C = (float*)Cp + (long)b * cBatch;
                const float bv = bias ? bias[col] : 0.f;
                #pragma unroll
                for (int mi = 0; mi < 2; mi++)
                    #pragma unroll
                    for (int r = 0; r < 4; r++)
                        C[(row0 + mi * 16 + r) * ldc + col] =
                            acc[qr][mi][ni][r] + bv;
            } else {
                // EPI 3: transposed V write. Cp = vt[4][1024][2048];
                // ldc = 2048 (s-stride), cBatch = 1024*2048. Blocks are
                // 256 rows, 2048%256==0 -> batch uniform per block.
                u16* C = (u16*)Cp + (m0 >> 11) * cBatch;
                const float bv = bias ? bias[col] : 0.f;
                #pragma unroll
                for (int mi = 0; mi < 2; mi++) {
                    const long sr = (row0 & 2047) + mi * 16;
                    us4 o;
                    #pragma unroll
                    for (int r = 0; r < 4; r++)
                        o[r] = f2bf(acc[qr][mi][ni][r] + bv);
                    *(us4*)(C + col * ldc + sr) = o;
                }
            }
        }
    }
}

// in-place masked row softmax over 2048 bf16 (f32 math). 1 block per row.
__global__ __launch_bounds__(256) void softmax2048(u16* __restrict__ S,
                                                   const int* __restrict__ mask) {
    const long row = blockIdx.x;
    u16* p = S + row * SEQ;
    const int* mrow = mask + row * SEQ;
    const int tid = threadIdx.x;

    short8 v = *(const short8*)(p + tid * 8);
    uint4 mw0 = *(const uint4*)(mrow + tid * 8);
    uint4 mw1 = *(const uint4*)(mrow + tid * 8 + 4);
    const unsigned int* mwv = (const unsigned int*)&mw0;

    float f[8];
    #pragma unroll
    for (int j = 0; j < 8; j++) {
        const unsigned int mv = (j < 4) ? mwv[j] : ((const unsigned int*)&mw1)[j - 4];
        f[j] = (mv == 0u) ? 1e-10f : bf2f((u16)v[j]);
    }

    float m = f[0];
    #pragma unroll
    for (int j = 1; j < 8; j++) m = fmaxf(m, f[j]);
    #pragma unroll
    for (int i = 1; i < 64; i <<= 1) m = fmaxf(m, __shfl_xor(m, i));

    __shared__ float redm[4], reds[4];
    if ((tid & 63) == 0) redm[tid >> 6] = m;
    __syncthreads();
    m = fmaxf(fmaxf(redm[0], redm[1]), fmaxf(redm[2], redm[3]));

    float e[8], s = 0.f;
    #pragma unroll
    for (int j = 0; j < 8; j++) { e[j] = __expf(f[j] - m); s += e[j]; }
    #pragma unroll
    for (int i = 1; i < 64; i <<= 1) s += __shfl_xor(s, i);
    if ((tid & 63) == 0) reds[tid >> 6] = s;
    __syncthreads();
    s = reds[0] + reds[1] + reds[2] + reds[3];

    const float inv = 1.f / s;
    short8 o;
    #pragma unroll
    for (int j = 0; j < 8; j++) o[j] = (short)f2bf(e[j] * inv);
    *(short8*)(p + tid * 8) = o;
}

extern "C" void kernel_launch(void* const* d_in, const int* in_sizes, int n_in,
                              void* d_out, int out_size, void* d_ws, size_t ws_size,
                              hipStream_t stream) {
    const float* x    = (const float*)d_in[0];
    const int*   mask = (const int*)d_in[1];
    const float* Wqkv = (const float*)d_in[2];
    const float* bqkv = (const float*)d_in[3];
    const float* Wout = (const float*)d_in[4];
    const float* bout = (const float*)d_in[5];
    float* out = (float*)d_out;

    char* ws = (char*)d_ws;
    // ws layout, total 102,760,448 bytes (round-11 layout):
    //   [0,        16777216) xh  bf16 [8192][1024]          (prep -> K1a/K1b)
    //   [16777216, 23068672) wqt bf16 [3072][1024]          (prep -> K1a/K1b)
    //   [0,        33554432) sc  bf16 [4][2048][2048]       (K2 -> K4; xh,wqt dead)
    //   [33554432, 35651584) wot bf16 [1024][1024]          (prep -> K5)
    //   [35651584, 69206016) qk  bf16 [8192][2048]          (K1a -> K2)
    //   [35651584, 52428800) attn bf16 [8192][1024]         (K4 -> K5; qk dead)
    //   [85983232,102760448) vt  bf16 [4][1024][2048]       (K1b -> K4)
    u16* xh   = (u16*)(ws + 0);
    u16* wqt  = (u16*)(ws + 16777216);
    u16* sc   = (u16*)(ws + 0);
    u16* wot  = (u16*)(ws + 33554432);
    u16* qk   = (u16*)(ws + 35651584);
    u16* attn = (u16*)(ws + 35651584);
    u16* vt   = (u16*)(ws + 85983232);

    // P: all input conversions/transposes, one launch (8192 blocks)
    prep<<<dim3(8192), 256, 0, stream>>>(x, xh, Wqkv, wqt, Wout, wot);

    // K1a: qk = x @ Wqkv[:, :2048] + bqkv[:2048]  (M=8192, N=2048, K=1024)
    //      16x32 = 512 blocks = 2.0 exact rounds
    gemm256n128<0><<<dim3(16, 32, 1), 512, 0, stream>>>(
        xh, 1024, 0, wqt, 1024, 0, qk, 2048, 0, bqkv, 1.f, 1024);

    // K1b: vt = (x @ Wqkv[:, 2048:] + bqkv[2048:])^T per batch
    //      (M=8192, N=1024, K=1024), transposed epilogue -> vt[b][d][s]
    //      8x32 = 256 blocks = 1.0 round
    gemm256n128<3><<<dim3(8, 32, 1), 512, 0, stream>>>(
        xh, 1024, 0, wqt + (long)2048 * 1024, 1024, 0,
        vt, SEQ, (long)1024 * SEQ, bqkv + 2048, 1.f, 1024);

    // K2: sc[b] = (Q[b] @ K[b]^T)/32   (M=N=2048, K=1024), bf16 out
    //     A = qk cols 0-1023 (Q), B = qk cols 1024-2047 (K), lda=ldb=2048
    //     16x8x4 = 512 blocks = 2.0 exact rounds
    gemm256n128<1><<<dim3(16, 8, NB), 512, 0, stream>>>(
        qk, 2048, (long)SEQ * 2048, qk + 1024, 2048, (long)SEQ * 2048,
        sc, SEQ, (long)SEQ * SEQ, nullptr, 0.03125f, 1024);

    // K3: masked softmax rows (mask==0 -> 1e-10, f32 math, bf16 storage)
    softmax2048<<<dim3(NB * SEQ), 256, 0, stream>>>(sc, mask);

    // K4: attn[b] = P[b] @ V[b]   (M=2048, N=1024, K=2048), bf16 out
    //     8x8x4 = 256 blocks = 1.0 round
    gemm256n128<0><<<dim3(8, 8, NB), 512, 0, stream>>>(
        sc, SEQ, (long)SEQ * SEQ, vt, SEQ, (long)1024 * SEQ,
        attn, 1024, (long)SEQ * 1024, nullptr, 1.f, 2048);

    // K5: out = attn @ Wout + bout   (M=8192, N=1024, K=1024), f32 out
    //     8x32 = 256 blocks = 1.0 round
    gemm256n128<2><<<dim3(8, 32, 1), 512, 0, stream>>>(
        attn, 1024, 0, wot, 1024, 0, out, 1024, 0, bout, 1.f, 1024);
}